// Round 5
// baseline (244.547 us; speedup 1.0000x reference)
//
#include <hip/hip_runtime.h>

#define E_EDGES   1000000
#define NNODES    2048
#define HCH       128
#define KP        136            // w1t row stride in bf16 (global layout only)
#define TILE      64
#define NTILES    (E_EDGES / TILE)   // 15625 exact
#define NSPREAD   8
#define GRID_GEMM 512            // exactly 2 blocks/CU resident
#define ZVEC      (32 * 2048 * 64 / 4)   // 1048576 float4s
#define ZBLK      2048
#define WBLK      66             // w1t transpose blocks (66*256 = 132*128 exactly)

typedef short  shortx8 __attribute__((ext_vector_type(8)));
typedef float  floatx4 __attribute__((ext_vector_type(4)));

__device__ __forceinline__ unsigned short f2bf(float f) {
  union { float f; unsigned int u; } v; v.f = f;
  unsigned int r = (v.u + 0x7fffu + ((v.u >> 16) & 1u)) >> 16;
  return (unsigned short)r;
}

__device__ __forceinline__ void SB() { __builtin_amdgcn_sched_barrier(0); }

__device__ __forceinline__ unsigned pack_rows(int s, int d) {
  unsigned rs = (unsigned)s & 0xFFFFu;
  unsigned rd = (unsigned)(((s & ~(NNODES - 1)) | (d & (NNODES - 1)))) & 0xFFFFu; // dst uses src batch
  return rs | (rd << 16);
}

// ---------------------------------------------------------------- prep ----
__global__ void k_prep(const float* __restrict__ z, const float* __restrict__ W1,
                       const float* __restrict__ b1,
                       unsigned short* __restrict__ zb, unsigned short* __restrict__ w1t,
                       float* __restrict__ gstats, float* __restrict__ out) {
  int bid = blockIdx.x;
  if (bid < ZBLK) {
    const float4* z4 = (const float4*)z;
    ushort4* zb4 = (ushort4*)zb;
    for (int i = bid * 256 + threadIdx.x; i < ZVEC; i += ZBLK * 256) {
      float4 v = z4[i];
      ushort4 o;
      o.x = f2bf(v.x); o.y = f2bf(v.y); o.z = f2bf(v.z); o.w = f2bf(v.w);
      zb4[i] = o;
    }
    // zero out (for the OUT pass's atomicAdd combine): 1e6 floats = 250000 float4
    float4 zf = {0.f, 0.f, 0.f, 0.f};
    float4* o4 = (float4*)out;
    for (int i = bid * 256 + threadIdx.x; i < (E_EDGES / 4); i += ZBLK * 256) o4[i] = zf;
  } else if (bid < ZBLK + WBLK) {
    // W1T[n][k] = W1[k][n], parallel across 66 blocks (one elem/thread)
    int idx = (bid - ZBLK) * 256 + threadIdx.x;   // 0..16895 = 132*128
    int k = idx >> 7, n = idx & 127;
    w1t[n * KP + k] = f2bf(W1[idx]);
  } else {
    int tid = threadIdx.x;
    if (tid < 512) {   // pad k=132..135: bias at 132, zeros after
      int n = tid >> 2, kp = 132 + (tid & 3);
      w1t[n * KP + kp] = (kp == 132) ? f2bf(b1[n]) : (unsigned short)0;
    }
    for (int i = tid; i < NSPREAD * 2 * HCH; i += 256) gstats[i] = 0.f;
  }
}

// ---------------------------------------------------------------- gemm ----
// Barrier-free: per-wave PRIVATE double-buffered A staging via global_load_lds
// (8 KB/wave/buf), so the only sync is each wave's own counted s_waitcnt.
// Cross-wave channel combine (OUT) and stats flush use global atomicAdd.
// Wave (eh,nh): edges eh*32..+31, channels nh*64..+63 of each 64-edge tile.
// Per-iteration vmem issue (pinned by sched_barrier): ei 2 + glds 8 + attr 2
// = 12 (+8 atomics in OUT) -> steady wait vmcnt(12)/vmcnt(20) retires exactly
// tile-t's glds while t+1's staging stays in flight.
template<bool OUT>
__global__ __launch_bounds__(256, 2)
void k_gemm(const unsigned short* __restrict__ zb,
            const unsigned short* __restrict__ w1t,
            const int* __restrict__ ei,
            const float* __restrict__ attr,
            float* __restrict__ gstats,
            const float* __restrict__ gamma,
            const float* __restrict__ beta,
            const float* __restrict__ W2,
            const float* __restrict__ b2,
            float* __restrict__ out) {
  __shared__ __align__(16) unsigned short A[4 * 2 * 4096];   // 64 KB: [wave][buf][8KB]

  const int tid  = threadIdx.x;
  const int lane = tid & 63;
  const int wave = tid >> 6;
  const int l15  = lane & 15;
  const int quad = lane >> 4;
  const int eh   = wave >> 1;
  const int nh   = wave & 1;
  const int eown = eh * 32 + (lane >> 1);   // edge (within tile) whose rows this lane holds
  const int grid = GRID_GEMM;

  // glds lane constants: instr c writes buf row r_w=c*4+quad, slot s_w=l15;
  // slot s holds logical 16B chunk g = s ^ (r_w&7); e7 = (c*4+quad)&7 = quad|(4*(c&1))
  const unsigned g_even = (unsigned)(l15 ^ quad);
  const unsigned g_odd  = (unsigned)(l15 ^ (quad | 4));

  unsigned short* const Aw = (unsigned short*)A + wave * 8192;   // ushort units

  auto glds8 = [&](unsigned prow, int pbuf) {
#pragma unroll
    for (int c = 0; c < 8; ++c) {
      unsigned p = (unsigned)__shfl((int)prow, c * 8 + (quad << 1));
      unsigned g = (c & 1) ? g_odd : g_even;
      unsigned row = (g < 8u) ? (p & 0xFFFFu) : (p >> 16);
      const unsigned short* ga = zb + ((size_t)row << 6) + ((g & 7u) << 3);
      unsigned short* la = Aw + pbuf * 4096 + c * 512;   // wave-uniform base
      __builtin_amdgcn_global_load_lds(
          (const __attribute__((address_space(1))) unsigned int*)ga,
          (__attribute__((address_space(3))) unsigned int*)la, 16, 0, 0);
    }
  };

  // ---- B fragments in registers (quads 1-3 of bfr4 zeroed: annihilates the
  //      same-on-all-quads A attr fragment at k>=136)
  shortx8 bfr[4][4], bfr4[4];
#pragma unroll
  for (int nt = 0; nt < 4; ++nt) {
    const int ch = nh * 64 + nt * 16 + l15;
    const unsigned short* bp = w1t + ch * KP + quad * 8;
#pragma unroll
    for (int kk = 0; kk < 4; ++kk)
      bfr[nt][kk] = *(const shortx8*)(bp + kk * 32);
    bfr4[nt] = (quad == 0) ? *(const shortx8*)(w1t + ch * KP + 128)
                           : (shortx8){0, 0, 0, 0, 0, 0, 0, 0};
  }

  float ea[4], ebb[4], ew2[4], b2v = 0.f;
  float ssum[4] = {0.f, 0.f, 0.f, 0.f}, ssq[4] = {0.f, 0.f, 0.f, 0.f};
  if (OUT) {
#pragma unroll
    for (int nt = 0; nt < 4; ++nt) {
      int c = nh * 64 + nt * 16 + l15;
      float S = 0.f, Q = 0.f;
#pragma unroll
      for (int i = 0; i < NSPREAD; ++i) {
        S += gstats[i * 2 * HCH + c];
        Q += gstats[i * 2 * HCH + HCH + c];
      }
      float mu   = S * (1.0f / (float)E_EDGES);
      float var  = Q * (1.0f / (float)E_EDGES) - mu * mu;
      float rstd = rsqrtf(var + 1e-5f);
      float a = gamma[c] * rstd;
      ea[nt]  = a;
      ebb[nt] = beta[c] - mu * a;
      ew2[nt] = W2[c];
    }
    b2v = b2[0];
  }

  // ---- prologue: glds(t0), attr(t0); ei(t2) in flight; prow_use = rows(t1)
  const int t0 = blockIdx.x;
  int t1 = t0 + grid;     if (t1 > NTILES - 1) t1 = NTILES - 1;
  int t2 = t0 + 2 * grid; if (t2 > NTILES - 1) t2 = NTILES - 1;

  int s2, d2;
  unsigned prow_use;
  float4 avc0, avc1, avn0, avn1;
  {
    int sa = ei[t0 * TILE + eown], da = ei[E_EDGES + t0 * TILE + eown];
    int sb = ei[t1 * TILE + eown], db = ei[E_EDGES + t1 * TILE + eown];
    unsigned prow0 = pack_rows(sa, da);
    prow_use = pack_rows(sb, db);
    SB();
    s2 = ei[t2 * TILE + eown];
    d2 = ei[E_EDGES + t2 * TILE + eown];
    SB();
    glds8(prow0, 0);
    SB();
    avc0 = ((const float4*)attr)[t0 * TILE + eh * 32 + l15];
    avc1 = ((const float4*)attr)[t0 * TILE + eh * 32 + 16 + l15];
    SB();
  }

  int pp = 0;
  for (int tile = t0; ; ) {
    const bool more = (tile + grid) < NTILES;

    if (more) {
      unsigned prow_next = pack_rows(s2, d2);   // compiler-counted wait on ei
      SB();
      int tC = tile + 3 * grid; if (tC > NTILES - 1) tC = NTILES - 1;
      s2 = ei[tC * TILE + eown];                // 2 vmem
      d2 = ei[E_EDGES + tC * TILE + eown];
      SB();
      glds8(prow_use, pp ^ 1);                  // 8 vmem
      prow_use = prow_next;
      SB();
      int tn = tile + grid;
      avn0 = ((const float4*)attr)[tn * TILE + eh * 32 + l15];        // 2 vmem
      avn1 = ((const float4*)attr)[tn * TILE + eh * 32 + 16 + l15];
      SB();
      if (OUT) asm volatile("s_waitcnt vmcnt(20)" ::: "memory");
      else     asm volatile("s_waitcnt vmcnt(12)" ::: "memory");
      SB();
    } else {
      SB();
      asm volatile("s_waitcnt vmcnt(0)" ::: "memory");
      SB();
    }

    // ---- A fragments from private LDS buffer pp (inline-asm ds_read so the
    //      compiler can't insert a conservative vmcnt for glds aliasing)
    const unsigned bb = (unsigned)(size_t)Aw + (unsigned)(pp * 8192);   // byte addr
    shortx8 afr[2][4];
#pragma unroll
    for (int mt = 0; mt < 2; ++mt) {
      const int r = mt * 16 + l15;
      const unsigned rb = bb + (unsigned)(r * 256);
#pragma unroll
      for (int kk = 0; kk < 4; ++kk) {
        unsigned ad = rb + (unsigned)((((kk * 4 + quad) ^ (r & 7)) << 4));
        asm volatile("ds_read_b128 %0, %1" : "=v"(afr[mt][kk]) : "v"(ad));
      }
    }
    asm volatile("s_waitcnt lgkmcnt(0)" ::: "memory");
    SB();   // rule 18: keep MFMA below the lgkm wait

    floatx4 acc[2][4];
#pragma unroll
    for (int mt = 0; mt < 2; ++mt)
#pragma unroll
      for (int nt = 0; nt < 4; ++nt)
        acc[mt][nt] = (floatx4){0.f, 0.f, 0.f, 0.f};

#pragma unroll
    for (int kk = 0; kk < 4; ++kk)
#pragma unroll
      for (int mt = 0; mt < 2; ++mt)
#pragma unroll
        for (int nt = 0; nt < 4; ++nt)
          acc[mt][nt] = __builtin_amdgcn_mfma_f32_16x16x32_bf16(
              afr[mt][kk], bfr[nt][kk], acc[mt][nt], 0, 0, 0);

    {   // kk=4: attr+bias (A same on all quads; bfr4 zeroed on quads 1-3)
      shortx8 a4[2];
      a4[0] = (shortx8){(short)f2bf(avc0.x), (short)f2bf(avc0.y), (short)f2bf(avc0.z),
                        (short)f2bf(avc0.w), (short)0x3F80, 0, 0, 0};
      a4[1] = (shortx8){(short)f2bf(avc1.x), (short)f2bf(avc1.y), (short)f2bf(avc1.z),
                        (short)f2bf(avc1.w), (short)0x3F80, 0, 0, 0};
#pragma unroll
      for (int mt = 0; mt < 2; ++mt)
#pragma unroll
        for (int nt = 0; nt < 4; ++nt)
          acc[mt][nt] = __builtin_amdgcn_mfma_f32_16x16x32_bf16(
              a4[mt], bfr4[nt], acc[mt][nt], 0, 0, 0);
    }

    // ---- epilogue
    if (!OUT) {
      // C/D layout: col = lane&15 (channel), row = quad*4 + reg (edge)
#pragma unroll
      for (int nt = 0; nt < 4; ++nt) {
        float s = 0.f, qq = 0.f;
#pragma unroll
        for (int mt = 0; mt < 2; ++mt)
#pragma unroll
          for (int r = 0; r < 4; ++r) {
            float h = acc[mt][nt][r];
            s += h; qq += h * h;
          }
        ssum[nt] += s; ssq[nt] += qq;
      }
    } else {
#pragma unroll
      for (int mt = 0; mt < 2; ++mt)
#pragma unroll
        for (int r = 0; r < 4; ++r) {
          float t = 0.f;
#pragma unroll
          for (int nt = 0; nt < 4; ++nt) {
            float h = acc[mt][nt][r];
            float p = ea[nt] * h + ebb[nt];
            p = (p >= 0.f) ? p : 0.2f * p;
            t += p * ew2[nt];
          }
          t += __shfl_xor(t, 1);
          t += __shfl_xor(t, 2);
          t += __shfl_xor(t, 4);
          t += __shfl_xor(t, 8);   // sum over this wave's 64 channels
          if (l15 == 0) {          // 8 atomic instrs/iter (counted in vmcnt)
            int el = eh * 32 + mt * 16 + quad * 4 + r;
            atomicAdd(&out[tile * TILE + el], (nh == 0) ? (t + b2v) : t);
          }
        }
    }

    if (!more) break;
    avc0 = avn0; avc1 = avn1;
    pp ^= 1;
    tile += grid;
  }

  if (!OUT) {   // flush stats straight to gstats (no LDS, no syncthreads)
    float* gs = gstats + (blockIdx.x & (NSPREAD - 1)) * 2 * HCH;
#pragma unroll
    for (int nt = 0; nt < 4; ++nt) {
      float s = ssum[nt], qq = ssq[nt];
      s += __shfl_xor(s, 16); s += __shfl_xor(s, 32);
      qq += __shfl_xor(qq, 16); qq += __shfl_xor(qq, 32);
      if (quad == 0) {
        atomicAdd(&gs[nh * 64 + nt * 16 + l15], s);
        atomicAdd(&gs[HCH + nh * 64 + nt * 16 + l15], qq);
      }
    }
  }
}

// -------------------------------------------------------------- launch ----
extern "C" void kernel_launch(void* const* d_in, const int* in_sizes, int n_in,
                              void* d_out, int out_size, void* d_ws, size_t ws_size,
                              hipStream_t stream) {
  const float* z     = (const float*)d_in[0];
  const float* attr  = (const float*)d_in[1];
  const float* W1    = (const float*)d_in[2];
  const float* b1    = (const float*)d_in[3];
  const float* gamma = (const float*)d_in[4];
  const float* beta  = (const float*)d_in[5];
  const float* W2    = (const float*)d_in[6];
  const float* b2    = (const float*)d_in[7];
  const int*   ei    = (const int*)d_in[8];
  float* out = (float*)d_out;

  char* ws = (char*)d_ws;
  unsigned short* zb  = (unsigned short*)ws;                 // 8,388,608 B
  unsigned short* w1t = (unsigned short*)(ws + 8388608);     //    34,816 B
  float* gstats       = (float*)(ws + 8423424);              //     8,192 B

  k_prep<<<ZBLK + WBLK + 1, 256, 0, stream>>>(z, W1, b1, zb, w1t, gstats, out);
  k_gemm<false><<<GRID_GEMM, 256, 0, stream>>>(zb, w1t, ei, attr, gstats,
                                               gamma, beta, W2, b2, nullptr);
  k_gemm<true><<<GRID_GEMM, 256, 0, stream>>>(zb, w1t, ei, attr, gstats,
                                              gamma, beta, W2, b2, out);
}